// Round 3
// baseline (497.935 us; speedup 1.0000x reference)
//
#include <hip/hip_runtime.h>
#include <hip/hip_bf16.h>
#include <hip/hip_fp16.h>

// 2-layer Elman RNN, S=64 B=64 H=E=512 V=10000.
// cvt weights->f16, gather X, [GEMM A0p=perm(X@W0^T)] -> [recur L0] ->
// [GEMM B1p=perm(H0@W1^T)] -> [recur L1] -> [GEMM logits=H1@Wd^T].
// Recurrence: 4 blocks (16 batch rows each), zero inter-block sync.
// U: kk0..11 pinned in VGPRs (asm), kk12..15 in LDS. h double-buffered in
// XOR-swizzled LDS. MFMA operands swapped (Z=U.h^T) so each lane owns
// (1 row x 4 consecutive cols) -> b64 LDS writes + reg-direct Hh export.

typedef _Float16 f16;
typedef _Float16 f16x2 __attribute__((ext_vector_type(2)));
typedef _Float16 f16x8 __attribute__((ext_vector_type(8)));
typedef float fvec4 __attribute__((ext_vector_type(4)));
typedef float f32x4 __attribute__((ext_vector_type(4)));
typedef unsigned int u32;
typedef u32 u32x2 __attribute__((ext_vector_type(2)));

__device__ __forceinline__ f32x4 mfma16(f16x8 a, f16x8 b, f32x4 c) {
    return __builtin_amdgcn_mfma_f32_16x16x32_f16(a, b, c, 0, 0, 0);
}

__device__ __forceinline__ f16x8 cvt_f16x8(fvec4 a, fvec4 b) {
    f16x8 r;
    r[0] = (f16)a[0]; r[1] = (f16)a[1]; r[2] = (f16)a[2]; r[3] = (f16)a[3];
    r[4] = (f16)b[0]; r[5] = (f16)b[1]; r[6] = (f16)b[2]; r[7] = (f16)b[3];
    return r;
}

// ---- fp32 -> f16 convert, 8 elems/thread ----
__global__ void cvt_f32_f16(const float* __restrict__ src, f16* __restrict__ dst, int n8) {
    int i = blockIdx.x * 256 + threadIdx.x;
    if (i >= n8) return;
    const fvec4* p = (const fvec4*)(src + (size_t)i * 8);
    *(f16x8*)(dst + (size_t)i * 8) = cvt_f16x8(p[0], p[1]);
}

// ---- Wd (10000x512) -> f16 padded to 10112 rows (zero pad) ----
__global__ void cvt_wd(const float* __restrict__ src, f16* __restrict__ dst) {
    int i = blockIdx.x * 256 + threadIdx.x;
    if (i >= 647168) return;
    if (i < 640000) {
        const fvec4* p = (const fvec4*)(src + (size_t)i * 8);
        *(f16x8*)(dst + (size_t)i * 8) = cvt_f16x8(p[0], p[1]);
    } else {
        f16x8 z = {};
        *(f16x8*)(dst + (size_t)i * 8) = z;
    }
}

// ---- gather X = f16(emb[tokens]) : (4096, 512) ----
__global__ void gather_x(const int* __restrict__ toks, const float* __restrict__ emb,
                         f16* __restrict__ xb) {
    int i = blockIdx.x * 256 + threadIdx.x;
    if (i >= 262144) return;
    int row = i >> 6, seg = i & 63;
    int tok = toks[row];
    const fvec4* p = (const fvec4*)(emb + (size_t)tok * 512 + seg * 8);
    *(f16x8*)(xb + (size_t)row * 512 + seg * 8) = cvt_f16x8(p[0], p[1]);
}

// ---- GEMM: C = A(M,512)f16 @ Bm(Npad,512)f16^T + bias1 + bias2 ----
// MODE 0: C row-major (M,N).  MODE 1: permuted fragment layout for recur:
// idx = (((t*4+g)*8+w)*64 + lane)*16 + nt*4 + r  with lane=(l15>>2)*16+l4*4+rr.
template <int MODE>
__global__ __launch_bounds__(256) void gemm_bt(
    const f16* __restrict__ A, const f16* __restrict__ Bm,
    const float* __restrict__ bias1, const float* __restrict__ bias2,
    float* __restrict__ C, int N)
{
    const int tM = blockIdx.x * 128;
    const int tN = blockIdx.y * 128;
    const int tid = threadIdx.x;
    const int l = tid & 63, w = tid >> 6;
    const int wr = w >> 1, wc = w & 1;
    const int l15 = l & 15, l4 = l >> 4;

    __shared__ f16 As[128 * 40];
    __shared__ f16 Bs[128 * 40];

    f32x4 acc[4][4] = {};

    for (int ks = 0; ks < 16; ++ks) {
        const int k0 = ks * 32;
        __syncthreads();
#pragma unroll
        for (int it = 0; it < 2; ++it) {
            int c = tid + it * 256;
            int row = c >> 2, seg = c & 3;
            *(f16x8*)(&As[row * 40 + seg * 8]) =
                *(const f16x8*)(A + (size_t)(tM + row) * 512 + k0 + seg * 8);
            *(f16x8*)(&Bs[row * 40 + seg * 8]) =
                *(const f16x8*)(Bm + (size_t)(tN + row) * 512 + k0 + seg * 8);
        }
        __syncthreads();
        f16x8 af[4], bf[4];
#pragma unroll
        for (int m = 0; m < 4; ++m)
            af[m] = *(const f16x8*)(&As[(wr * 64 + m * 16 + l15) * 40 + 8 * l4]);
#pragma unroll
        for (int n = 0; n < 4; ++n)
            bf[n] = *(const f16x8*)(&Bs[(wc * 64 + n * 16 + l15) * 40 + 8 * l4]);
#pragma unroll
        for (int m = 0; m < 4; ++m)
#pragma unroll
            for (int n = 0; n < 4; ++n)
                acc[m][n] = mfma16(af[m], bf[n], acc[m][n]);
    }

    if (MODE == 0) {
#pragma unroll
        for (int n = 0; n < 4; ++n) {
            int col = tN + wc * 64 + n * 16 + l15;
            if (col >= N) continue;
            float bsum = (bias1 ? bias1[col] : 0.f) + (bias2 ? bias2[col] : 0.f);
#pragma unroll
            for (int m = 0; m < 4; ++m)
#pragma unroll
                for (int r = 0; r < 4; ++r) {
                    int row = tM + wr * 64 + m * 16 + l4 * 4 + r;
                    C[(size_t)row * N + col] = acc[m][n][r] + bsum;
                }
        }
    } else {
        const int t  = blockIdx.x * 2 + wr;   // row>>6
        const int wp = blockIdx.y * 2 + wc;   // col>>6
        const int lp_hi = (l15 >> 2) * 16;    // dest-lane l4' * 16
        const int rp = l15 & 3;               // dest reg r'
#pragma unroll
        for (int n = 0; n < 4; ++n) {
            int col = tN + wc * 64 + n * 16 + l15;
            float bsum = bias1[col] + bias2[col];
#pragma unroll
            for (int m = 0; m < 4; ++m) {     // m = batch group g
#pragma unroll
                for (int r = 0; r < 4; ++r) { // mrow = l4*4+r
                    int lanep = lp_hi + l4 * 4 + r;
                    size_t idx = ((((size_t)t * 4 + m) * 8 + wp) * 64 + lanep) * 16
                                 + n * 4 + rp;
                    C[idx] = acc[m][n][r] + bsum;
                }
            }
        }
    }
}

// ---- Recurrence: h_t = tanh(ain_t + U @ h_{t-1}^T), one block per 16 rows ----
__global__ __launch_bounds__(512, 2) void recur_kernel(
    const float* __restrict__ A0p,   // permuted preactivation (t,g,w,lane,16)
    const float* __restrict__ U,     // (512,512) fp32 row-major U[c][k]
    const float* __restrict__ h0,    // (64,512) initial hidden
    f16* __restrict__ Hh,            // (4096,512) f16 history out (row-major)
    float* __restrict__ outTail)     // (64,512) fp32 final hidden out
{
    const int g = blockIdx.x;
    const int tid = threadIdx.x;
    const int l = tid & 63, w = tid >> 6;
    const int l15 = l & 15, l4 = l >> 4;
    const int colbase = w * 64;

    __shared__ __align__(16) char smem[163840];
    char* hsb  = smem;                // 2 x (16 rows x 1024B), XOR-swizzled
    char* ldsB = smem + 32768;        // U kk12..15: [w][nt][kk][lane*16B]

    // ---- one-time: U fragments (lane l: U[colbase+nt*16+l15][kk*32+8*l4+j]) ----
    f16x8 bf[4][12];
#pragma unroll
    for (int nt = 0; nt < 4; ++nt) {
        const float* urow = U + (size_t)(colbase + nt * 16 + l15) * 512 + 8 * l4;
#pragma unroll
        for (int kk = 0; kk < 12; ++kk) {
            const fvec4* p = (const fvec4*)(urow + kk * 32);
            bf[nt][kk] = cvt_f16x8(p[0], p[1]);
            asm volatile("" : "+v"(bf[nt][kk]));   // pin: no remat/spill-to-reload
        }
#pragma unroll
        for (int kk = 12; kk < 16; ++kk) {
            const fvec4* p = (const fvec4*)(urow + kk * 32);
            *(f16x8*)(ldsB + ((w * 4 + nt) * 4 + (kk - 12)) * 1024 + l * 16) =
                cvt_f16x8(p[0], p[1]);
        }
    }
    // ---- one-time: stage h_init into buffer 0 (swizzled) ----
    for (int c = tid; c < 1024; c += 512) {
        int row = c >> 6, seg = c & 63;
        const fvec4* p = (const fvec4*)(h0 + (size_t)(g * 16 + row) * 512 + seg * 8);
        *(f16x8*)(hsb + row * 1024 + ((seg * 16) ^ ((row & 7) << 4))) =
            cvt_f16x8(p[0], p[1]);
    }
    __syncthreads();

    const int sw = (l15 & 7) << 4;
    const int rowbase = l15 * 1024;

    for (int t = 0; t < 64; ++t) {
        // ain prefetch (coalesced, matches acc fragment layout exactly)
        const float* ab = A0p + (((size_t)t * 4 + g) * 8 + w) * 1024 + l * 16;
        f32x4 ain[4];
#pragma unroll
        for (int nt = 0; nt < 4; ++nt) ain[nt] = *(const fvec4*)(ab + nt * 4);

        const char* hrd = hsb + (t & 1) * 16384 + rowbase;
        f32x4 acc[4] = {};
#pragma unroll
        for (int kk = 0; kk < 12; ++kk) {
            f16x8 h = *(const f16x8*)(hrd + ((kk * 64 + l4 * 16) ^ sw));
            acc[0] = mfma16(bf[0][kk], h, acc[0]);
            acc[1] = mfma16(bf[1][kk], h, acc[1]);
            acc[2] = mfma16(bf[2][kk], h, acc[2]);
            acc[3] = mfma16(bf[3][kk], h, acc[3]);
        }
#pragma unroll
        for (int kk = 12; kk < 16; ++kk) {
            f16x8 h = *(const f16x8*)(hrd + ((kk * 64 + l4 * 16) ^ sw));
#pragma unroll
            for (int nt = 0; nt < 4; ++nt) {
                f16x8 u = *(const f16x8*)(ldsB + ((w * 4 + nt) * 4 + (kk - 12)) * 1024 + l * 16);
                acc[nt] = mfma16(u, h, acc[nt]);
            }
        }

        // tanh(x) = 1 - 2/(e^{2x}+1); lane owns row m=l15, cols c0..c0+3 per nt
        char* hwr = hsb + (((t & 1) ^ 1) * 16384) + rowbase;
        f16* hrow = Hh + ((size_t)t * 64 + g * 16 + l15) * 512;
#pragma unroll
        for (int nt = 0; nt < 4; ++nt) {
            f32x4 v;
#pragma unroll
            for (int r = 0; r < 4; ++r) {
                float x = acc[nt][r] + ain[nt][r];
                float e = __expf(2.0f * x);
                v[r] = 1.0f - 2.0f * __builtin_amdgcn_rcpf(e + 1.0f);
            }
            u32 p0 = __builtin_bit_cast(u32, __builtin_amdgcn_cvt_pkrtz(v[0], v[1]));
            u32 p1 = __builtin_bit_cast(u32, __builtin_amdgcn_cvt_pkrtz(v[2], v[3]));
            u32x2 pk; pk[0] = p0; pk[1] = p1;
            int c0 = colbase + nt * 16 + l4 * 4;
            *(u32x2*)(hwr + ((c0 * 2) ^ sw)) = pk;          // h_t -> LDS (b64)
            *(u32x2*)(hrow + c0) = pk;                      // Hh export (8B)
            if (t == 63)
                *(f32x4*)(outTail + (size_t)(g * 16 + l15) * 512 + c0) = v;
        }
        __syncthreads();
    }
}

extern "C" void kernel_launch(void* const* d_in, const int* in_sizes, int n_in,
                              void* d_out, int out_size, void* d_ws, size_t ws_size,
                              hipStream_t stream) {
    const int*   toks   = (const int*)d_in[0];
    const float* hidden = (const float*)d_in[1];
    const float* emb    = (const float*)d_in[2];
    const float* W0  = (const float*)d_in[3];
    const float* bW0 = (const float*)d_in[4];
    const float* W1  = (const float*)d_in[5];
    const float* bW1 = (const float*)d_in[6];
    const float* U0  = (const float*)d_in[7];
    const float* bU0 = (const float*)d_in[8];
    const float* U1  = (const float*)d_in[9];
    const float* bU1 = (const float*)d_in[10];
    const float* Wd  = (const float*)d_in[11];
    const float* bd  = (const float*)d_in[12];
    float* out = (float*)d_out;

    char* ws = (char*)d_ws;
    f16*   W0h  = (f16*)(ws + 0);               // 524288
    f16*   W1h  = (f16*)(ws + 524288);          // 524288
    f16*   Wdh  = (f16*)(ws + 1048576);         // 10354688
    f16*   Xb   = (f16*)(ws + 11403264);        // 4194304
    f16*   H0h  = (f16*)(ws + 15597568);        // 4194304
    f16*   H1h  = (f16*)(ws + 19791872);        // 4194304
    float* A0   = (float*)(ws + 23986176);      // 8388608 (permuted)
    float* B1   = (float*)(ws + 32374784);      // 8388608 (permuted)

    cvt_f32_f16<<<128, 256, 0, stream>>>(W0, W0h, 32768);
    cvt_f32_f16<<<128, 256, 0, stream>>>(W1, W1h, 32768);
    cvt_wd<<<2528, 256, 0, stream>>>(Wd, Wdh);
    gather_x<<<1024, 256, 0, stream>>>(toks, emb, Xb);

    gemm_bt<1><<<dim3(32, 4), 256, 0, stream>>>(Xb, W0h, bW0, bU0, A0, 512);
    recur_kernel<<<4, 512, 0, stream>>>(A0, U0, hidden, H0h, out + 40960000);
    gemm_bt<1><<<dim3(32, 4), 256, 0, stream>>>(H0h, W1h, bW1, bU1, B1, 512);
    recur_kernel<<<4, 512, 0, stream>>>(B1, U1, hidden + 32768, H1h,
                                        out + 40960000 + 32768);
    gemm_bt<0><<<dim3(32, 79), 256, 0, stream>>>(H1h, Wdh, bd, nullptr, out, 10000);
}